// Round 2
// baseline (293.800 us; speedup 1.0000x reference)
//
#include <hip/hip_runtime.h>
#include <hip/hip_cooperative_groups.h>
#include <math.h>

namespace cg = cooperative_groups;

// Problem constants (B=1)
#define S 2048
#define DM 512
#define WIN 64
#define NX (S * DM)                        // 1,048,576
#define ATTN_SCALE 0.17677669529663687f    // 1/sqrt(32)
#define NBLK 512                           // fused grid size (2 blocks/CU)

typedef __attribute__((ext_vector_type(8))) short short8;   // 8 x bf16 (4 VGPR)
typedef __attribute__((ext_vector_type(4))) float floatx4;  // MFMA acc

__device__ __forceinline__ unsigned short f2bf(float f) {
  unsigned int u = __float_as_uint(f);
  unsigned int r = (u + 0x7FFFu + ((u >> 16) & 1u)) >> 16;   // RNE
  return (unsigned short)r;
}

// ---------------------------------------------------------------------------
// Stage A body: one float4 fp32->bf16 item (x then Wq|Wk|Wv|Wo).
// ---------------------------------------------------------------------------
__device__ __forceinline__ void convert_item(
    size_t i4, const float* __restrict__ x, const float* __restrict__ Wq,
    const float* __restrict__ Wk, const float* __restrict__ Wv,
    const float* __restrict__ Wo, unsigned short* __restrict__ xbf,
    unsigned short* __restrict__ wbf) {
  const float* src; unsigned short* dst; size_t off;
  if (i4 < (size_t)NX) {
    src = x; dst = xbf; off = i4;
  } else {
    size_t r = i4 - (size_t)NX;
    int wsel = (int)(r >> 18);                // / (512*512)
    src = wsel == 0 ? Wq : wsel == 1 ? Wk : wsel == 2 ? Wv : Wo;
    dst = wbf + ((size_t)wsel << 18);
    off = r & 262143;
  }
  float4 f = *(const float4*)(src + off);
  ushort4 o;
  o.x = f2bf(f.x); o.y = f2bf(f.y); o.z = f2bf(f.z); o.w = f2bf(f.w);
  *(ushort4*)(dst + off) = o;
}

// ---------------------------------------------------------------------------
// bf16 MFMA GEMM tile: C[64x64 at (row0,col0)] += A[M,K] * B[N,K]^T.
// 256 threads = 4 waves in 2x2, each wave 32x32 via 2x2 mfma_f32_16x16x32_bf16.
// LDS granule XOR-swizzle: row r, 16B-granule g stored at g ^ (r & 7).
// (verified body from the 110us production kernel, unchanged math)
// ---------------------------------------------------------------------------
__device__ __forceinline__ void gemm_tile64(
    const unsigned short* __restrict__ Abf,
    const unsigned short* __restrict__ B,
    float* __restrict__ C, int N, int K, int row0, int col0,
    unsigned short* As, unsigned short* Bs) {
  const int tid  = threadIdx.x;
  const int lane = tid & 63;
  const int w    = tid >> 6;       // wave id 0..3
  const int wr   = w >> 1;         // wave row 0..1
  const int wc   = w & 1;          // wave col 0..1
  const int quad = lane >> 4;      // 0..3
  const int lc   = lane & 15;

  const int srow = tid >> 3;
  const int sg   = tid & 7;                    // granule within row
  const int scol = sg * 8;                     // element col in global tile
  const int sw0  = (sg ^ (srow & 7)) * 8;      // swizzled LDS elem col

  floatx4 acc[2][2] = {};

  for (int k0 = 0; k0 < K; k0 += 64) {
    short8 a0 = *(const short8*)&Abf[(size_t)(row0 + srow) * K + k0 + scol];
    short8 a1 = *(const short8*)&Abf[(size_t)(row0 + srow + 32) * K + k0 + scol];
    short8 b0 = *(const short8*)&B[(size_t)(col0 + srow) * K + k0 + scol];
    short8 b1 = *(const short8*)&B[(size_t)(col0 + srow + 32) * K + k0 + scol];
    __syncthreads();   // previous iteration's LDS reads complete
    *(short8*)&As[srow * 64 + sw0] = a0;
    *(short8*)&As[(srow + 32) * 64 + sw0] = a1;   // (srow+32)&7 == srow&7
    *(short8*)&Bs[srow * 64 + sw0] = b0;
    *(short8*)&Bs[(srow + 32) * 64 + sw0] = b1;
    __syncthreads();

#pragma unroll
    for (int s = 0; s < 2; ++s) {
      const int gk = s * 4 + quad;            // k-granule 0..7
      short8 aF[2], bF[2];
#pragma unroll
      for (int i = 0; i < 2; ++i) {
        int m = wr * 32 + i * 16 + lc;
        aF[i] = *(const short8*)&As[m * 64 + (gk ^ (m & 7)) * 8];
      }
#pragma unroll
      for (int j = 0; j < 2; ++j) {
        int n = wc * 32 + j * 16 + lc;
        bF[j] = *(const short8*)&Bs[n * 64 + (gk ^ (n & 7)) * 8];
      }
#pragma unroll
      for (int i = 0; i < 2; ++i)
#pragma unroll
        for (int j = 0; j < 2; ++j)
          acc[i][j] = __builtin_amdgcn_mfma_f32_16x16x32_bf16(
              aF[i], bF[j], acc[i][j], 0, 0, 0);
    }
  }

  // C/D layout: col = lane&15, row = quad*4 + reg  [verified m89/m91]
#pragma unroll
  for (int i = 0; i < 2; ++i)
#pragma unroll
    for (int j = 0; j < 2; ++j) {
      int col = col0 + wc * 32 + j * 16 + lc;
#pragma unroll
      for (int r = 0; r < 4; ++r) {
        int row = row0 + wr * 32 + i * 16 + quad * 4 + r;
        C[(size_t)row * N + col] = acc[i][j][r];
      }
    }
}

// ---------------------------------------------------------------------------
// Stage C body: sliding-window per-channel softmax, one 64-row x 32-ch tile.
// Stages k/v rows [i0-63, i0+63] x 32 ch in LDS (2 x 16.25 KB).
// ---------------------------------------------------------------------------
#define SWIN_ITEM(EDGE)                                                       \
  {                                                                           \
    float l0 = 0.f, l1 = 0.f, l2 = 0.f, l3 = 0.f;                             \
    float a0 = 0.f, a1 = 0.f, a2 = 0.f, a3 = 0.f;                             \
    _Pragma("unroll 4")                                                       \
    for (int jj = 0; jj < WIN; jj += 4) {                                     \
      _Pragma("unroll")                                                       \
      for (int u = 0; u < 4; ++u) {                                           \
        const float kv = ks[base + (jj + u) * 32];                            \
        const float vv = vs[base + (jj + u) * 32];                            \
        float p = __expf(qv * kv);                                            \
        if (EDGE) p = (jj + u >= th) ? p : 0.f;                               \
        const float pv = p * vv;                                              \
        if (u == 0)      { l0 += p; a0 += pv; }                               \
        else if (u == 1) { l1 += p; a1 += pv; }                               \
        else if (u == 2) { l2 += p; a2 += pv; }                               \
        else             { l3 += p; a3 += pv; }                               \
      }                                                                       \
    }                                                                         \
    const float r = (a0 + a1 + a2 + a3) / (l0 + l1 + l2 + l3);                \
    o[(size_t)(i0 + ii) * DM + c] = f2bf(r);                                  \
  }

__device__ __forceinline__ void swin_tile(
    const float* __restrict__ q, const float* __restrict__ k,
    const float* __restrict__ v, unsigned short* __restrict__ o,
    int i0, int c0, float* ks, float* vs) {
  const int t = threadIdx.x;

  for (int vi = t; vi < 2 * 127 * 8; vi += 256) {
    const int a = vi >= 1016;                    // 0: k, 1: v
    const int r = (vi - (a ? 1016 : 0)) >> 3;    // panel row 0..126
    const int g = vi & 7;                        // float4 within row
    int gr = i0 - 63 + r;
    gr = gr < 0 ? 0 : gr;                        // clamp (masked in compute)
    const float4 f =
        *(const float4*)((a ? v : k) + (size_t)gr * DM + c0 + g * 4);
    *(float4*)((a ? vs : ks) + (r << 5) + g * 4) = f;
  }
  __syncthreads();

  const int cl = t & 31;
  const int c  = c0 + cl;

  if (i0 == 0) {
#pragma unroll
    for (int item = 0; item < 8; ++item) {
      const int ii = (t >> 5) + item * 8;                 // 0..63
      const float qv = q[(size_t)(i0 + ii) * DM + c] * ATTN_SCALE;
      const int base = ii * 32 + cl;                      // LDS row ii..ii+63
      const int th = 63 - ii;                             // jj >= th is valid
      SWIN_ITEM(true)
    }
  } else {
#pragma unroll
    for (int item = 0; item < 8; ++item) {
      const int ii = (t >> 5) + item * 8;
      const float qv = q[(size_t)(i0 + ii) * DM + c] * ATTN_SCALE;
      const int base = ii * 32 + cl;
      const int th = 0;                                   // unused
      SWIN_ITEM(false)
    }
  }
}

// ---------------------------------------------------------------------------
// Fused cooperative kernel: convert -> QKV -> swin -> proj, 3 grid syncs.
// 512 blocks x 256 threads; LDS = 32.5 KB union -> 2 blocks/CU co-resident
// (LDS 160 KB/CU, 2048 thr/CU: wide co-residency margin).
// ---------------------------------------------------------------------------
__global__ __launch_bounds__(256) void fused_all(
    const float* x, const float* Wq, const float* Wk, const float* Wv,
    const float* Wo, unsigned short* xbf, unsigned short* wbf,
    float* q, float* kk, float* vv, float* out) {
  cg::grid_group grid = cg::this_grid();
  __shared__ __align__(16) unsigned char lds[32512];

  // ---- stage A: fp32 -> bf16 (2M elements, 4 float4-items per thread)
  {
    size_t tidg = (size_t)blockIdx.x * 256 + threadIdx.x;   // 0..131071
#pragma unroll
    for (int it = 0; it < 4; ++it)
      convert_item((tidg + (size_t)it * (NBLK * 256)) * 4,
                   x, Wq, Wk, Wv, Wo, xbf, wbf);
  }
  grid.sync();

  // ---- stage B: QKV GEMM, 768 (= 3 z * 32 by * 8 bx) 64x64 tiles
  {
    unsigned short* As = (unsigned short*)lds;
    unsigned short* Bs = (unsigned short*)(lds + 8192);
    for (int t = blockIdx.x; t < 768; t += NBLK) {
      const int z = t >> 8, rem = t & 255;
      gemm_tile64(xbf, wbf + ((size_t)z << 18), q + (size_t)z * NX,
                  DM, DM, (rem >> 3) << 6, (rem & 7) << 6, As, Bs);
    }
  }
  grid.sync();

  // ---- stage C: sliding-window softmax, 512 tiles (16 c x 32 i), 1/block
  {
    float* ks = (float*)lds;
    float* vs = (float*)(lds + 16256);
    swin_tile(q, kk, vv, xbf /* attnbf reuse */,
              (blockIdx.x >> 4) << 6, (blockIdx.x & 15) << 5, ks, vs);
  }
  grid.sync();

  // ---- stage D: output projection, 256 tiles
  if (blockIdx.x < 256) {
    unsigned short* As = (unsigned short*)lds;
    unsigned short* Bs = (unsigned short*)(lds + 8192);
    const int t = blockIdx.x;
    gemm_tile64(xbf, wbf + ((size_t)3 << 18), out, DM, DM,
                (t >> 3) << 6, (t & 7) << 6, As, Bs);
  }
}

// ---------------------------------------------------------------------------
// Fallback wrappers (proven 4-launch path) in case cooperative launch fails.
// ---------------------------------------------------------------------------
__global__ __launch_bounds__(256) void convert_bf16(
    const float* __restrict__ x, const float* __restrict__ Wq,
    const float* __restrict__ Wk, const float* __restrict__ Wv,
    const float* __restrict__ Wo,
    unsigned short* __restrict__ xbf, unsigned short* __restrict__ wbf) {
  size_t i4 = ((size_t)blockIdx.x * 256 + threadIdx.x) * 4;
  convert_item(i4, x, Wq, Wk, Wv, Wo, xbf, wbf);
}

__global__ __launch_bounds__(256) void gemm_bf16(
    const unsigned short* __restrict__ Abf,
    const unsigned short* __restrict__ Bbase, int bstride,
    float* __restrict__ Cbase, int cstride, int N, int K) {
  __shared__ unsigned short As[64 * 64];
  __shared__ unsigned short Bs[64 * 64];
  gemm_tile64(Abf, Bbase + (size_t)blockIdx.z * bstride,
              Cbase + (size_t)blockIdx.z * cstride, N, K,
              blockIdx.y * 64, blockIdx.x * 64, As, Bs);
}

__global__ __launch_bounds__(256) void swin_attn_tiled(
    const float* __restrict__ q, const float* __restrict__ k,
    const float* __restrict__ v, unsigned short* __restrict__ o) {
  __shared__ float ks[127 * 32];
  __shared__ float vs[127 * 32];
  swin_tile(q, k, v, o, blockIdx.y * 64, blockIdx.x * 32, ks, vs);
}

// ---------------------------------------------------------------------------
// Launch
// ---------------------------------------------------------------------------
extern "C" void kernel_launch(void* const* d_in, const int* in_sizes, int n_in,
                              void* d_out, int out_size, void* d_ws, size_t ws_size,
                              hipStream_t stream) {
  const float* x  = (const float*)d_in[0];
  const float* Wq = (const float*)d_in[1];
  const float* Wk = (const float*)d_in[2];
  const float* Wv = (const float*)d_in[3];
  const float* Wo = (const float*)d_in[4];
  float* out = (float*)d_out;

  // ws layout (16 MB):
  //   q, k, v : 3 x 1M fp32 (12 MB); xbf: 1M bf16 (2 MB, reused as attn_bf16);
  //   wbf: 4 x 256K bf16 (2 MB)
  float* q = (float*)d_ws;
  float* kk = q + (size_t)NX;
  float* vv = kk + (size_t)NX;
  unsigned short* xbf = (unsigned short*)(vv + (size_t)NX);
  unsigned short* wbf = xbf + (size_t)NX;

  void* args[] = {(void*)&x, (void*)&Wq, (void*)&Wk, (void*)&Wv, (void*)&Wo,
                  (void*)&xbf, (void*)&wbf, (void*)&q, (void*)&kk, (void*)&vv,
                  (void*)&out};
  hipError_t e = hipLaunchCooperativeKernel(
      reinterpret_cast<void*>(fused_all), dim3(NBLK), dim3(256), args, 0,
      stream);
  if (e != hipSuccess) {
    // proven 4-launch fallback
    convert_bf16<<<dim3(2048), dim3(256), 0, stream>>>(x, Wq, Wk, Wv, Wo, xbf, wbf);
    gemm_bf16<<<dim3(DM / 64, S / 64, 3), dim3(256), 0, stream>>>(
        xbf, wbf, DM * DM, q, S * DM, DM, DM);
    swin_attn_tiled<<<dim3(DM / 32, S / 64), dim3(256), 0, stream>>>(q, kk, vv, xbf);
    gemm_bf16<<<dim3(DM / 64, S / 64, 1), dim3(256), 0, stream>>>(
        xbf, wbf + 3 * (size_t)DM * DM, 0, out, 0, DM, DM);
  }
}

// Round 3
// 109.656 us; speedup vs baseline: 2.6793x; 2.6793x over previous
//
#include <hip/hip_runtime.h>
#include <math.h>

// Problem constants (B=1)
#define S 2048
#define DM 512
#define WIN 64
#define NX (S * DM)                        // 1,048,576
#define ATTN_SCALE 0.17677669529663687f    // 1/sqrt(32)

typedef __attribute__((ext_vector_type(8))) short short8;   // 8 x bf16 (4 VGPR)
typedef __attribute__((ext_vector_type(4))) float floatx4;  // MFMA acc

typedef const __attribute__((address_space(1))) unsigned int guint;
typedef __attribute__((address_space(3))) unsigned int luint;

__device__ __forceinline__ unsigned short f2bf(float f) {
  unsigned int u = __float_as_uint(f);
  unsigned int r = (u + 0x7FFFu + ((u >> 16) & 1u)) >> 16;   // RNE
  return (unsigned short)r;
}

// ---------------------------------------------------------------------------
// Convert x (S*DM floats) and Wq|Wk|Wv|Wo (4 * DM*DM) to bf16.
// ---------------------------------------------------------------------------
__global__ __launch_bounds__(256) void convert_bf16(
    const float* __restrict__ x, const float* __restrict__ Wq,
    const float* __restrict__ Wk, const float* __restrict__ Wv,
    const float* __restrict__ Wo,
    unsigned short* __restrict__ xbf, unsigned short* __restrict__ wbf) {
  size_t i4 = ((size_t)blockIdx.x * 256 + threadIdx.x) * 4;
  const float* src; unsigned short* dst; size_t off;
  if (i4 < (size_t)NX) {
    src = x; dst = xbf; off = i4;
  } else {
    size_t r = i4 - (size_t)NX;
    int wsel = (int)(r >> 18);                // / (512*512)
    src = wsel == 0 ? Wq : wsel == 1 ? Wk : wsel == 2 ? Wv : Wo;
    dst = wbf + ((size_t)wsel << 18);
    off = r & 262143;
  }
  float4 f = *(const float4*)(src + off);
  ushort4 o;
  o.x = f2bf(f.x); o.y = f2bf(f.y); o.z = f2bf(f.z); o.w = f2bf(f.w);
  *(ushort4*)(dst + off) = o;
}

// ---------------------------------------------------------------------------
// bf16 MFMA GEMM: C[M,N] = A[M,K] * B[N,K]^T  (fp32 accumulate/output).
// 64x64 tile, BK=64, 4 waves in 2x2, each wave 32x32 via 2x2 of
// mfma_f32_16x16x32_bf16.
//
// Staging now uses global_load_lds width=16 (async global->LDS DMA, no VGPR
// round trip). gload_lds writes LDS linearly (wave base + lane*16B), so the
// granule XOR-swizzle [row][slot] <- global[row][slot ^ (row&7)] is realized
// by pre-swizzling the per-lane GLOBAL source granule (rule #21 / m173):
//   issue n covers LDS rows 8n..8n+7; lane l -> row 8n+(l>>3), slot l&7,
//   source granule (l&7) ^ (l>>3).  Read side identical to verified kernel:
//   granule gk of row m read at LDS slot gk ^ (m&7)  (involution).
// ---------------------------------------------------------------------------
__global__ __launch_bounds__(256) void gemm_bf16(
    const unsigned short* __restrict__ Abf,
    const unsigned short* __restrict__ Bbase, int bstride,
    float* __restrict__ Cbase, int cstride, int N, int K) {
  __shared__ unsigned short As[64 * 64];
  __shared__ unsigned short Bs[64 * 64];

  const unsigned short* B = Bbase + (size_t)blockIdx.z * bstride;
  float* C = Cbase + (size_t)blockIdx.z * cstride;

  const int row0 = blockIdx.y * 64;
  const int col0 = blockIdx.x * 64;
  const int tid  = threadIdx.x;
  const int lane = tid & 63;
  const int w    = tid >> 6;       // wave id 0..3
  const int wr   = w >> 1;         // wave row 0..1
  const int wc   = w & 1;          // wave col 0..1
  const int quad = lane >> 4;      // 0..3
  const int lc   = lane & 15;

  // --- gload_lds source/dest map: wave w handles issues {2w, 2w+1} each for
  // A and B; issue n = rows 8n..8n+7 of the tile.
  const int lr = lane >> 3;                    // local row 0..7 within issue
  const int sgr = (lane & 7) ^ lr;             // pre-swizzled source granule
  const int ra0 = 16 * w + lr;                 // tile row, issue 2w
  const int ra1 = 16 * w + 8 + lr;             // tile row, issue 2w+1
  const unsigned short* srcA0 = Abf + (size_t)(row0 + ra0) * K + sgr * 8;
  const unsigned short* srcA1 = Abf + (size_t)(row0 + ra1) * K + sgr * 8;
  const unsigned short* srcB0 = B   + (size_t)(col0 + ra0) * K + sgr * 8;
  const unsigned short* srcB1 = B   + (size_t)(col0 + ra1) * K + sgr * 8;
  luint* dstA0 = (luint*)(As + (2 * w) * 512);      // 512 shorts = 8 rows
  luint* dstA1 = (luint*)(As + (2 * w + 1) * 512);
  luint* dstB0 = (luint*)(Bs + (2 * w) * 512);
  luint* dstB1 = (luint*)(Bs + (2 * w + 1) * 512);

  floatx4 acc[2][2] = {};

  for (int k0 = 0; k0 < K; k0 += 64) {
    __syncthreads();   // previous iteration's LDS reads complete
    __builtin_amdgcn_global_load_lds((guint*)(const void*)(srcA0 + k0), dstA0, 16, 0, 0);
    __builtin_amdgcn_global_load_lds((guint*)(const void*)(srcA1 + k0), dstA1, 16, 0, 0);
    __builtin_amdgcn_global_load_lds((guint*)(const void*)(srcB0 + k0), dstB0, 16, 0, 0);
    __builtin_amdgcn_global_load_lds((guint*)(const void*)(srcB1 + k0), dstB1, 16, 0, 0);
    __syncthreads();   // per-wave vmcnt(0) drain before barrier -> LDS ready

#pragma unroll
    for (int s = 0; s < 2; ++s) {
      const int gk = s * 4 + quad;            // k-granule 0..7
      short8 aF[2], bF[2];
#pragma unroll
      for (int i = 0; i < 2; ++i) {
        int m = wr * 32 + i * 16 + lc;
        aF[i] = *(const short8*)&As[m * 64 + (gk ^ (m & 7)) * 8];
      }
#pragma unroll
      for (int j = 0; j < 2; ++j) {
        int n = wc * 32 + j * 16 + lc;
        bF[j] = *(const short8*)&Bs[n * 64 + (gk ^ (n & 7)) * 8];
      }
#pragma unroll
      for (int i = 0; i < 2; ++i)
#pragma unroll
        for (int j = 0; j < 2; ++j)
          acc[i][j] = __builtin_amdgcn_mfma_f32_16x16x32_bf16(
              aF[i], bF[j], acc[i][j], 0, 0, 0);
    }
  }

  // C/D layout: col = lane&15, row = quad*4 + reg  [verified m89/m91]
#pragma unroll
  for (int i = 0; i < 2; ++i)
#pragma unroll
    for (int j = 0; j < 2; ++j) {
      int col = col0 + wc * 32 + j * 16 + lc;
#pragma unroll
      for (int r = 0; r < 4; ++r) {
        int row = row0 + wr * 32 + i * 16 + quad * 4 + r;
        C[(size_t)row * N + col] = acc[i][j][r];
      }
    }
}

// ---------------------------------------------------------------------------
// Sliding-window per-channel softmax, LDS-tiled (verified R1 body, unchanged).
// Block = 64 query rows x 32 channels; stages k/v rows [i0-63, i0+63].
// ---------------------------------------------------------------------------
#define SWIN_ITEM(EDGE)                                                       \
  {                                                                           \
    float l0 = 0.f, l1 = 0.f, l2 = 0.f, l3 = 0.f;                             \
    float a0 = 0.f, a1 = 0.f, a2 = 0.f, a3 = 0.f;                             \
    _Pragma("unroll 4")                                                       \
    for (int jj = 0; jj < WIN; jj += 4) {                                     \
      _Pragma("unroll")                                                       \
      for (int u = 0; u < 4; ++u) {                                           \
        const float kv = ks[base + (jj + u) * 32];                            \
        const float vv = vs[base + (jj + u) * 32];                            \
        float p = __expf(qv * kv);                                            \
        if (EDGE) p = (jj + u >= th) ? p : 0.f;                               \
        const float pv = p * vv;                                              \
        if (u == 0)      { l0 += p; a0 += pv; }                               \
        else if (u == 1) { l1 += p; a1 += pv; }                               \
        else if (u == 2) { l2 += p; a2 += pv; }                               \
        else             { l3 += p; a3 += pv; }                               \
      }                                                                       \
    }                                                                         \
    const float r = (a0 + a1 + a2 + a3) / (l0 + l1 + l2 + l3);                \
    o[(size_t)(i0 + ii) * DM + c] = f2bf(r);                                  \
  }

__global__ __launch_bounds__(256) void swin_attn_tiled(
    const float* __restrict__ q, const float* __restrict__ k,
    const float* __restrict__ v, unsigned short* __restrict__ o) {
  __shared__ float ks[127 * 32];
  __shared__ float vs[127 * 32];

  const int i0 = blockIdx.y * 64;      // query-row tile
  const int c0 = blockIdx.x * 32;      // channel tile
  const int t  = threadIdx.x;

  for (int vi = t; vi < 2 * 127 * 8; vi += 256) {
    const int a = vi >= 1016;                    // 0: k, 1: v
    const int r = (vi - (a ? 1016 : 0)) >> 3;    // panel row 0..126
    const int g = vi & 7;                        // float4 within row
    int gr = i0 - 63 + r;
    gr = gr < 0 ? 0 : gr;                        // clamp (masked in compute)
    const float4 f =
        *(const float4*)((a ? v : k) + (size_t)gr * DM + c0 + g * 4);
    *(float4*)((a ? vs : ks) + (r << 5) + g * 4) = f;
  }
  __syncthreads();

  const int cl = t & 31;
  const int c  = c0 + cl;

  if (blockIdx.y == 0) {
#pragma unroll
    for (int item = 0; item < 8; ++item) {
      const int ii = (t >> 5) + item * 8;                 // 0..63
      const float qv = q[(size_t)(i0 + ii) * DM + c] * ATTN_SCALE;
      const int base = ii * 32 + cl;                      // LDS row ii..ii+63
      const int th = 63 - ii;                             // jj >= th is valid
      SWIN_ITEM(true)
    }
  } else {
#pragma unroll
    for (int item = 0; item < 8; ++item) {
      const int ii = (t >> 5) + item * 8;
      const float qv = q[(size_t)(i0 + ii) * DM + c] * ATTN_SCALE;
      const int base = ii * 32 + cl;
      const int th = 0;                                   // unused
      SWIN_ITEM(false)
    }
  }
}

// ---------------------------------------------------------------------------
// Launch — proven 4-dispatch structure (R2 showed harness overhead is fixed
// per-iteration, not per-dispatch; cooperative fusion regressed 2x).
// ---------------------------------------------------------------------------
extern "C" void kernel_launch(void* const* d_in, const int* in_sizes, int n_in,
                              void* d_out, int out_size, void* d_ws, size_t ws_size,
                              hipStream_t stream) {
  const float* x  = (const float*)d_in[0];
  const float* Wq = (const float*)d_in[1];
  const float* Wk = (const float*)d_in[2];
  const float* Wv = (const float*)d_in[3];
  const float* Wo = (const float*)d_in[4];
  float* out = (float*)d_out;

  // ws layout (16 MB):
  //   q, k, v : 3 x 1M fp32 (12 MB)
  //   xbf     : 1M bf16 (2 MB)  -- reused as attn_bf16 after QKV GEMM
  //   wbf     : 4 x 256K bf16 (2 MB)
  float* q = (float*)d_ws;
  float* kk = q + (size_t)NX;
  float* vv = kk + (size_t)NX;
  unsigned short* xbf = (unsigned short*)(vv + (size_t)NX);
  unsigned short* wbf = xbf + (size_t)NX;
  unsigned short* attnbf = xbf;   // reuse after x is consumed

  // 1) fp32 -> bf16 conversions (2M elements, 4/thread)
  convert_bf16<<<dim3(2048), dim3(256), 0, stream>>>(x, Wq, Wk, Wv, Wo, xbf, wbf);

  // 2) fused QKV: C_z = x * W_z^T, z = 0,1,2
  gemm_bf16<<<dim3(DM / 64, S / 64, 3), dim3(256), 0, stream>>>(
      xbf, wbf, DM * DM, q, S * DM, DM, DM);

  // 3) sliding-window per-channel softmax (LDS-tiled) -> bf16
  swin_attn_tiled<<<dim3(DM / 32, S / 64), dim3(256), 0, stream>>>(
      q, kk, vv, attnbf);

  // 4) output projection: out = attn * Wo^T
  gemm_bf16<<<dim3(DM / 64, S / 64, 1), dim3(256), 0, stream>>>(
      attnbf, wbf + 3 * (size_t)DM * DM, 0, out, 0, DM, DM);
}

// Round 4
// 107.002 us; speedup vs baseline: 2.7457x; 1.0248x over previous
//
#include <hip/hip_runtime.h>
#include <math.h>

// Problem constants (B=1)
#define S 2048
#define DM 512
#define WIN 64
#define NX (S * DM)                        // 1,048,576
#define ATTN_SCALE 0.17677669529663687f    // 1/sqrt(32)
#define QSCALE 0.25500526964836844f        // ATTN_SCALE * log2(e)

typedef __attribute__((ext_vector_type(8))) short short8;   // 8 x bf16 (4 VGPR)
typedef __attribute__((ext_vector_type(4))) float floatx4;  // MFMA acc

__device__ __forceinline__ unsigned short f2bf(float f) {
  unsigned int u = __float_as_uint(f);
  unsigned int r = (u + 0x7FFFu + ((u >> 16) & 1u)) >> 16;   // RNE
  return (unsigned short)r;
}

// Raw v_exp_f32 (2^x). gfx9-lineage VALU is interlocked; single VOP1.
__device__ __forceinline__ float fast_exp2(float x) {
  float r;
  asm("v_exp_f32 %0, %1" : "=v"(r) : "v"(x));
  return r;
}

// ---------------------------------------------------------------------------
// Convert x (S*DM floats) and Wq|Wk|Wv|Wo (4 * DM*DM) to bf16.
// ---------------------------------------------------------------------------
__global__ __launch_bounds__(256) void convert_bf16(
    const float* __restrict__ x, const float* __restrict__ Wq,
    const float* __restrict__ Wk, const float* __restrict__ Wv,
    const float* __restrict__ Wo,
    unsigned short* __restrict__ xbf, unsigned short* __restrict__ wbf) {
  size_t i4 = ((size_t)blockIdx.x * 256 + threadIdx.x) * 4;
  const float* src; unsigned short* dst; size_t off;
  if (i4 < (size_t)NX) {
    src = x; dst = xbf; off = i4;
  } else {
    size_t r = i4 - (size_t)NX;
    int wsel = (int)(r >> 18);                // / (512*512)
    src = wsel == 0 ? Wq : wsel == 1 ? Wk : wsel == 2 ? Wv : Wo;
    dst = wbf + ((size_t)wsel << 18);
    off = r & 262143;
  }
  float4 f = *(const float4*)(src + off);
  ushort4 o;
  o.x = f2bf(f.x); o.y = f2bf(f.y); o.z = f2bf(f.z); o.w = f2bf(f.w);
  *(ushort4*)(dst + off) = o;
}

// ---------------------------------------------------------------------------
// bf16 MFMA GEMM: C[M,N] = A[M,K] * B[N,K]^T  (fp32 accumulate/output).
// 64x64 tile, BK=64, 4 waves in 2x2, each wave 32x32 via 2x2 of
// mfma_f32_16x16x32_bf16.  LDS granule XOR-swizzle: row r, granule g at
// g ^ (r & 7).
//
// T14 stage-split pipeline: registers hold K-tile t while LDS holds t-1.
//   barrier -> ds_write regs(t) -> barrier -> ISSUE loads(t+1) -> compute(t)
// The global-load latency of tile t+1 hides under the ds_read+MFMA phase of
// tile t (plus ~3 co-resident blocks/CU of TLP), instead of being exposed
// serially as in the previous stage->barrier->compute structure.
// ---------------------------------------------------------------------------
__global__ __launch_bounds__(256) void gemm_bf16(
    const unsigned short* __restrict__ Abf,
    const unsigned short* __restrict__ Bbase, int bstride,
    float* __restrict__ Cbase, int cstride, int N, int K) {
  __shared__ unsigned short As[64 * 64];
  __shared__ unsigned short Bs[64 * 64];

  const unsigned short* B = Bbase + (size_t)blockIdx.z * bstride;
  float* C = Cbase + (size_t)blockIdx.z * cstride;

  const int row0 = blockIdx.y * 64;
  const int col0 = blockIdx.x * 64;
  const int tid  = threadIdx.x;
  const int lane = tid & 63;
  const int w    = tid >> 6;       // wave id 0..3
  const int wr   = w >> 1;         // wave row 0..1
  const int wc   = w & 1;          // wave col 0..1
  const int quad = lane >> 4;      // 0..3
  const int lc   = lane & 15;

  // staging map: thread -> (row srow, 16B granule tid&7), covers 32 rows/pass
  const int srow = tid >> 3;
  const int sg   = tid & 7;                    // granule within row
  const int scol = sg * 8;                     // element col in global tile
  const int sw0  = (sg ^ (srow & 7)) * 8;      // swizzled LDS elem col

  const unsigned short* pa0 = &Abf[(size_t)(row0 + srow) * K + scol];
  const unsigned short* pa1 = &Abf[(size_t)(row0 + srow + 32) * K + scol];
  const unsigned short* pb0 = &B[(size_t)(col0 + srow) * K + scol];
  const unsigned short* pb1 = &B[(size_t)(col0 + srow + 32) * K + scol];

  floatx4 acc[2][2] = {};

  // prologue: K-tile 0 into registers
  short8 a0 = *(const short8*)pa0;
  short8 a1 = *(const short8*)pa1;
  short8 b0 = *(const short8*)pb0;
  short8 b1 = *(const short8*)pb1;

  for (int k0 = 0; k0 < K; k0 += 64) {
    __syncthreads();   // previous iteration's LDS reads complete
    *(short8*)&As[srow * 64 + sw0] = a0;
    *(short8*)&As[(srow + 32) * 64 + sw0] = a1;   // (srow+32)&7 == srow&7
    *(short8*)&Bs[srow * 64 + sw0] = b0;
    *(short8*)&Bs[(srow + 32) * 64 + sw0] = b1;
    __syncthreads();

    if (k0 + 64 < K) {   // issue next K-tile loads; latency hides under MFMA
      a0 = *(const short8*)(pa0 + k0 + 64);
      a1 = *(const short8*)(pa1 + k0 + 64);
      b0 = *(const short8*)(pb0 + k0 + 64);
      b1 = *(const short8*)(pb1 + k0 + 64);
    }

#pragma unroll
    for (int s = 0; s < 2; ++s) {
      const int gk = s * 4 + quad;            // k-granule 0..7
      short8 aF[2], bF[2];
#pragma unroll
      for (int i = 0; i < 2; ++i) {
        int m = wr * 32 + i * 16 + lc;
        aF[i] = *(const short8*)&As[m * 64 + (gk ^ (m & 7)) * 8];
      }
#pragma unroll
      for (int j = 0; j < 2; ++j) {
        int n = wc * 32 + j * 16 + lc;
        bF[j] = *(const short8*)&Bs[n * 64 + (gk ^ (n & 7)) * 8];
      }
#pragma unroll
      for (int i = 0; i < 2; ++i)
#pragma unroll
        for (int j = 0; j < 2; ++j)
          acc[i][j] = __builtin_amdgcn_mfma_f32_16x16x32_bf16(
              aF[i], bF[j], acc[i][j], 0, 0, 0);
    }
  }

  // C/D layout: col = lane&15, row = quad*4 + reg  [verified m89/m91]
#pragma unroll
  for (int i = 0; i < 2; ++i)
#pragma unroll
    for (int j = 0; j < 2; ++j) {
      int col = col0 + wc * 32 + j * 16 + lc;
#pragma unroll
      for (int r = 0; r < 4; ++r) {
        int row = row0 + wr * 32 + i * 16 + quad * 4 + r;
        C[(size_t)row * N + col] = acc[i][j][r];
      }
    }
}

// ---------------------------------------------------------------------------
// Sliding-window per-channel softmax, LDS-tiled, issue-slimmed.
// Block = 64 query rows x 32 channels; stages k/v rows [i0-63, i0+63].
// k,v interleaved as float2 rows padded to 33 (row stride 264 B): both the
// b64 writes and the b64 reads land <=2 lanes/bank (free aliasing, m136).
// Per window item: 1 ds_read_b64 + mul + v_exp_f32 + fma + add
// (exp folded to exp2 with log2e pre-multiplied into the q scalar).
// ---------------------------------------------------------------------------
#define SWIN_ITEM(EDGE)                                                       \
  {                                                                           \
    float l0 = 0.f, l1 = 0.f, l2 = 0.f, l3 = 0.f;                             \
    float a0 = 0.f, a1 = 0.f, a2 = 0.f, a3 = 0.f;                             \
    _Pragma("unroll 4")                                                       \
    for (int jj = 0; jj < WIN; jj += 4) {                                     \
      _Pragma("unroll")                                                       \
      for (int u = 0; u < 4; ++u) {                                           \
        const float2 kv2 = kvs[base + (jj + u) * 33];                         \
        float p = fast_exp2(qvl * kv2.x);                                     \
        if (EDGE) p = (jj + u >= th) ? p : 0.f;                               \
        if (u == 0)      { l0 += p; a0 = fmaf(p, kv2.y, a0); }                \
        else if (u == 1) { l1 += p; a1 = fmaf(p, kv2.y, a1); }                \
        else if (u == 2) { l2 += p; a2 = fmaf(p, kv2.y, a2); }                \
        else             { l3 += p; a3 = fmaf(p, kv2.y, a3); }                \
      }                                                                       \
    }                                                                         \
    const float r = (a0 + a1 + a2 + a3) / (l0 + l1 + l2 + l3);                \
    o[(size_t)(i0 + ii) * DM + c] = f2bf(r);                                  \
  }

__global__ __launch_bounds__(256) void swin_attn_tiled(
    const float* __restrict__ q, const float* __restrict__ k,
    const float* __restrict__ v, unsigned short* __restrict__ o) {
  __shared__ float2 kvs[127 * 33];     // 33.5 KB, padded row stride

  const int i0 = blockIdx.y * 64;      // query-row tile
  const int c0 = blockIdx.x * 32;      // channel tile
  const int t  = threadIdx.x;

  // Stage rows [i0-63, i0+63] x cols [c0, c0+32): 1016 items, ~4/thread,
  // each = 2 coalesced float4 loads + 4 interleaved float2 LDS writes.
  for (int vi = t; vi < 127 * 8; vi += 256) {
    const int r = vi >> 3;                       // panel row 0..126
    const int g = vi & 7;                        // float4 within row
    int gr = i0 - 63 + r;
    gr = gr < 0 ? 0 : gr;                        // clamp (masked in compute)
    const float4 kf = *(const float4*)(k + (size_t)gr * DM + c0 + g * 4);
    const float4 vf = *(const float4*)(v + (size_t)gr * DM + c0 + g * 4);
    float2* dst = &kvs[r * 33 + g * 4];
    dst[0] = make_float2(kf.x, vf.x);
    dst[1] = make_float2(kf.y, vf.y);
    dst[2] = make_float2(kf.z, vf.z);
    dst[3] = make_float2(kf.w, vf.w);
  }
  __syncthreads();

  const int cl = t & 31;
  const int c  = c0 + cl;

  if (blockIdx.y == 0) {
#pragma unroll
    for (int item = 0; item < 8; ++item) {
      const int ii = (t >> 5) + item * 8;                 // 0..63
      const float qvl = q[(size_t)(i0 + ii) * DM + c] * QSCALE;
      const int base = ii * 33 + cl;                      // panel rows ii..ii+63
      const int th = 63 - ii;                             // jj >= th is valid
      SWIN_ITEM(true)
    }
  } else {
#pragma unroll
    for (int item = 0; item < 8; ++item) {
      const int ii = (t >> 5) + item * 8;
      const float qvl = q[(size_t)(i0 + ii) * DM + c] * QSCALE;
      const int base = ii * 33 + cl;
      const int th = 0;                                   // unused
      SWIN_ITEM(false)
    }
  }
}

// ---------------------------------------------------------------------------
// Launch — proven 4-dispatch structure (R2: overhead is fixed per-iteration,
// not per-dispatch; cooperative fusion regressed 2x).
// ---------------------------------------------------------------------------
extern "C" void kernel_launch(void* const* d_in, const int* in_sizes, int n_in,
                              void* d_out, int out_size, void* d_ws, size_t ws_size,
                              hipStream_t stream) {
  const float* x  = (const float*)d_in[0];
  const float* Wq = (const float*)d_in[1];
  const float* Wk = (const float*)d_in[2];
  const float* Wv = (const float*)d_in[3];
  const float* Wo = (const float*)d_in[4];
  float* out = (float*)d_out;

  // ws layout (16 MB):
  //   q, k, v : 3 x 1M fp32 (12 MB)
  //   xbf     : 1M bf16 (2 MB)  -- reused as attn_bf16 after QKV GEMM
  //   wbf     : 4 x 256K bf16 (2 MB)
  float* q = (float*)d_ws;
  float* kk = q + (size_t)NX;
  float* vv = kk + (size_t)NX;
  unsigned short* xbf = (unsigned short*)(vv + (size_t)NX);
  unsigned short* wbf = xbf + (size_t)NX;
  unsigned short* attnbf = xbf;   // reuse after x is consumed

  // 1) fp32 -> bf16 conversions (2M elements, 4/thread)
  convert_bf16<<<dim3(2048), dim3(256), 0, stream>>>(x, Wq, Wk, Wv, Wo, xbf, wbf);

  // 2) fused QKV: C_z = x * W_z^T, z = 0,1,2
  gemm_bf16<<<dim3(DM / 64, S / 64, 3), dim3(256), 0, stream>>>(
      xbf, wbf, DM * DM, q, S * DM, DM, DM);

  // 3) sliding-window per-channel softmax (LDS-tiled) -> bf16
  swin_attn_tiled<<<dim3(DM / 32, S / 64), dim3(256), 0, stream>>>(
      q, kk, vv, attnbf);

  // 4) output projection: out = attn * Wo^T
  gemm_bf16<<<dim3(DM / 64, S / 64, 1), dim3(256), 0, stream>>>(
      attnbf, wbf + 3 * (size_t)DM * DM, 0, out, 0, DM, DM);
}